// Round 11
// baseline (267.498 us; speedup 1.0000x reference)
//
#include <hip/hip_runtime.h>
#include <hip/hip_bf16.h>
#include <math.h>

#define D_MODEL 1024
#define SEQ     2048
#define BATCH   2
#define NHEAD   16
#define DKH     64
#define BH      (BATCH * NHEAD)   // 32

typedef unsigned short u16;
typedef unsigned int   u32;
typedef __bf16 bf16x8 __attribute__((ext_vector_type(8)));
typedef float  f32x4  __attribute__((ext_vector_type(4)));

#define MFMA16(a, b, c) __builtin_amdgcn_mfma_f32_16x16x32_bf16((a), (b), (c), 0, 0, 0)
#define AS1 __attribute__((address_space(1)))
#define AS3 __attribute__((address_space(3)))

// 1/(8*ln2): folded into Q so softmax is exp2(s) with no fma and no shift
#define QSCALE 0.18033688f

__device__ __forceinline__ u16 f2bf(float x) {
    u32 u = __float_as_uint(x);
    u += 0x7fffu + ((u >> 16) & 1u);   // RNE (finite data)
    return (u16)(u >> 16);
}
__device__ __forceinline__ float bf2f(u16 b) {
    return __uint_as_float(((u32)b) << 16);
}
// async global->LDS, 16B/lane; lds dest wave-uniform (lane*16 implicit)
__device__ __forceinline__ void gl16(const u16* g, void* lds) {
    __builtin_amdgcn_global_load_lds((const AS1 u32*)g, (AS3 u32*)lds, 16, 0, 0);
}

// ---------------------------------------------------------------------------
// Conversions, one launch:
//   blocks [0, 4096)    : x fp32 -> bf16 (hi only)
//   blocks [4096, 5120) : W [K][N] fp32 -> WT bf16 [N][K]; hi for all 4,
//                         lo only for Wo (out-proj keeps 2-term precision)
// ---------------------------------------------------------------------------
__global__ __launch_bounds__(256) void conv_all(
    const float* __restrict__ x, u16* __restrict__ Xh, int n4,
    const float* __restrict__ W0, const float* __restrict__ W1,
    const float* __restrict__ W2, const float* __restrict__ W3,
    u16* __restrict__ Hq, u16* __restrict__ Hk, u16* __restrict__ Hv,
    u16* __restrict__ Ho, u16* __restrict__ Lo)
{
    const int t = threadIdx.x;
    if ((int)blockIdx.x < 4096) {
        int i = blockIdx.x * 256 + t;
        if (i >= n4) return;
        float4 v = reinterpret_cast<const float4*>(x)[i];
        uint2 H;
        H.x = f2bf(v.x) | ((u32)f2bf(v.y) << 16);
        H.y = f2bf(v.z) | ((u32)f2bf(v.w) << 16);
        reinterpret_cast<uint2*>(Xh)[i] = H;
        return;
    }
    int id = blockIdx.x - 4096;          // 0..1023
    int bx = id & 15, by = (id >> 4) & 15, bz = id >> 8;
    const float* W; u16* Ht;
    if (bz == 0)      { W = W0; Ht = Hq; }
    else if (bz == 1) { W = W1; Ht = Hk; }
    else if (bz == 2) { W = W2; Ht = Hv; }
    else              { W = W3; Ht = Ho; }

    __shared__ float T[64][65];
    const int n0 = bx * 64, k0 = by * 64;
    #pragma unroll
    for (int i = 0; i < 4; ++i) {
        int f = t + i * 256;
        int kr = f >> 4, ns = (f & 15) * 4;
        float4 v = *reinterpret_cast<const float4*>(&W[(size_t)(k0 + kr) * D_MODEL + n0 + ns]);
        T[kr][ns + 0] = v.x; T[kr][ns + 1] = v.y; T[kr][ns + 2] = v.z; T[kr][ns + 3] = v.w;
    }
    __syncthreads();
    #pragma unroll
    for (int i = 0; i < 4; ++i) {
        int f = t + i * 256;
        int nr = f >> 4, ks = (f & 15) * 4;
        u16 hh[4], ll[4];
        #pragma unroll
        for (int j = 0; j < 4; ++j) {
            float xv = T[ks + j][nr];
            u16 hb = f2bf(xv);
            hh[j] = hb;
            ll[j] = f2bf(xv - bf2f(hb));
        }
        uint2 H, L;
        H.x = hh[0] | ((u32)hh[1] << 16); H.y = hh[2] | ((u32)hh[3] << 16);
        L.x = ll[0] | ((u32)ll[1] << 16); L.y = ll[2] | ((u32)ll[3] << 16);
        size_t o = (size_t)(n0 + nr) * D_MODEL + k0 + ks;
        *reinterpret_cast<uint2*>(&Ht[o]) = H;
        if (bz == 3) *reinterpret_cast<uint2*>(&Lo[o]) = L;
    }
}

// ---------------------------------------------------------------------------
// Fused QKV GEMM, 1-term bf16: C = Xh @ Bh^T + bias.  (Outputs are rounded
// to bf16 anyway; output quantization dominates the dropped lo-terms.)
// 512 threads (8 waves, 2/SIMD); 128x128 tile; wave tile 32x64.
// Staged: A | Bq | Bk | Bv = 32 KB/buf, dbuf 64 KB; 24 MFMA/wave-iter.
// Q pre-scaled by QSCALE.
// ---------------------------------------------------------------------------
__global__ __launch_bounds__(512, 2) void gemm_qkv(
    const u16* __restrict__ AhG,
    const u16* __restrict__ Bqh, const u16* __restrict__ Bkh, const u16* __restrict__ Bvh,
    const float* __restrict__ bq, const float* __restrict__ bk, const float* __restrict__ bv,
    u16* __restrict__ Qb, u16* __restrict__ Kb, u16* __restrict__ Vb)
{
    constexpr int K = D_MODEL, N = D_MODEL;
    __shared__ u16 LB[2][16384];   // per buf: A | Bq | Bk | Bv (8 KB each)

    const int tid  = threadIdx.x;
    const int wv   = tid >> 6;
    const int lane = tid & 63;
    const int quad = lane >> 4;
    const int l16  = lane & 15;
    const int wm   = wv >> 1, wn = wv & 1;
    const int brow = blockIdx.y * 128, bcol = blockIdx.x * 128;

    // staging: 32 chunks of 1 KB; wave w -> chunks 4w..4w+3
    const u16* sp[4];
    int sldb[4];
    #pragma unroll
    for (int j = 0; j < 4; ++j) {
        int c = wv * 4 + j, a = c >> 3, cc = c & 7;
        int row = cc * 16 + (lane >> 2);
        int gseg = (lane & 3) ^ ((lane >> 3) & 3);
        const u16* p;
        if (a == 0)      p = AhG;
        else if (a == 1) p = Bqh;
        else if (a == 2) p = Bkh;
        else             p = Bvh;
        int rbase = (a == 0) ? brow : bcol;
        sp[j]   = p + (size_t)(rbase + row) * K + gseg * 8;
        sldb[j] = a * 8192 + cc * 1024;
    }

    int aro[2], bro[4];
    #pragma unroll
    for (int i = 0; i < 2; ++i) {
        int mr = wm * 32 + i * 16 + l16;
        aro[i] = mr * 64 + ((quad ^ ((mr >> 1) & 3)) * 16);
    }
    #pragma unroll
    for (int i = 0; i < 4; ++i) {
        int nr = wn * 64 + i * 16 + l16;
        bro[i] = nr * 64 + ((quad ^ ((nr >> 1) & 3)) * 16);
    }

    f32x4 acc[3][2][4] = {};

    #pragma unroll
    for (int j = 0; j < 4; ++j)
        gl16(sp[j], (char*)LB[0] + sldb[j]);

    for (int it = 0; it < K / 32; ++it) {
        const int cur = it & 1;
        __syncthreads();
        if (it + 1 < K / 32) {
            const int nxt = cur ^ 1;
            const int k1 = (it + 1) * 32;
            #pragma unroll
            for (int j = 0; j < 4; ++j)
                gl16(sp[j] + k1, (char*)LB[nxt] + sldb[j]);
        }

        bf16x8 ah[2];
        #pragma unroll
        for (int i = 0; i < 2; ++i)
            ah[i] = *reinterpret_cast<const bf16x8*>((const char*)LB[cur] + aro[i]);
        #pragma unroll
        for (int m = 0; m < 3; ++m) {
            const int bb = (1 + m) * 8192;
            bf16x8 bh[4];
            #pragma unroll
            for (int i = 0; i < 4; ++i)
                bh[i] = *reinterpret_cast<const bf16x8*>((const char*)LB[cur] + bb + bro[i]);
            #pragma unroll
            for (int mi = 0; mi < 2; ++mi)
                #pragma unroll
                for (int ni = 0; ni < 4; ++ni)
                    acc[m][mi][ni] = MFMA16(ah[mi], bh[ni], acc[m][mi][ni]);
        }
    }

    // epilogue: Q pre-scaled for exp2-softmax; all flat bf16
    #pragma unroll
    for (int m = 0; m < 3; ++m) {
        const float* bias = (m == 0) ? bq : (m == 1) ? bk : bv;
        u16* out = (m == 0) ? Qb : (m == 1) ? Kb : Vb;
        const float sc = (m == 0) ? QSCALE : 1.0f;
        #pragma unroll
        for (int mi = 0; mi < 2; ++mi) {
            #pragma unroll
            for (int ni = 0; ni < 4; ++ni) {
                int col = bcol + wn * 64 + ni * 16 + l16;
                float bvv = bias[col];
                #pragma unroll
                for (int r = 0; r < 4; ++r) {
                    int row = brow + wm * 32 + mi * 16 + quad * 4 + r;
                    out[(size_t)row * N + col] = f2bf((acc[m][mi][ni][r] + bvv) * sc);
                }
            }
        }
    }
}

// ---------------------------------------------------------------------------
// Out-proj GEMM, 2-term: out = Ctx @ (Woh+Wol)^T + bo, fp32 out.
// ---------------------------------------------------------------------------
__global__ __launch_bounds__(512, 2) void gemm_oproj(
    const u16* __restrict__ AhG, const u16* __restrict__ Bh, const u16* __restrict__ Bl,
    const float* __restrict__ bias, float* __restrict__ Cf)
{
    constexpr int K = D_MODEL, N = D_MODEL;
    __shared__ u16 LB[2][12288];   // per buf: A | Bh | Bl (8KB each)

    const int tid  = threadIdx.x;
    const int wv   = tid >> 6;
    const int lane = tid & 63;
    const int quad = lane >> 4;
    const int l16  = lane & 15;
    const int wm   = wv >> 1, wn = wv & 1;
    const int brow = blockIdx.y * 128, bcol = blockIdx.x * 128;

    const u16* sp[3];
    int sldb[3];
    #pragma unroll
    for (int j = 0; j < 3; ++j) {
        int c = wv * 3 + j, a = c >> 3, cc = c & 7;
        int row = cc * 16 + (lane >> 2);
        int gseg = (lane & 3) ^ ((lane >> 3) & 3);
        const u16* p = (a == 0) ? AhG : (a == 1) ? Bh : Bl;
        int rbase = (a == 0) ? brow : bcol;
        sp[j]   = p + (size_t)(rbase + row) * K + gseg * 8;
        sldb[j] = a * 8192 + cc * 1024;
    }

    int aro[2], bro[4];
    #pragma unroll
    for (int i = 0; i < 2; ++i) {
        int mr = wm * 32 + i * 16 + l16;
        aro[i] = mr * 64 + ((quad ^ ((mr >> 1) & 3)) * 16);
    }
    #pragma unroll
    for (int i = 0; i < 4; ++i) {
        int nr = wn * 64 + i * 16 + l16;
        bro[i] = nr * 64 + ((quad ^ ((nr >> 1) & 3)) * 16);
    }

    f32x4 acc[2][4] = {};

    #pragma unroll
    for (int j = 0; j < 3; ++j)
        gl16(sp[j], (char*)LB[0] + sldb[j]);

    for (int it = 0; it < K / 32; ++it) {
        const int cur = it & 1;
        __syncthreads();
        if (it + 1 < K / 32) {
            const int nxt = cur ^ 1;
            const int k1 = (it + 1) * 32;
            #pragma unroll
            for (int j = 0; j < 3; ++j)
                gl16(sp[j] + k1, (char*)LB[nxt] + sldb[j]);
        }

        bf16x8 ah[2], bh[4], bl[4];
        #pragma unroll
        for (int i = 0; i < 2; ++i)
            ah[i] = *reinterpret_cast<const bf16x8*>((const char*)LB[cur] + aro[i]);
        #pragma unroll
        for (int i = 0; i < 4; ++i) {
            bh[i] = *reinterpret_cast<const bf16x8*>((const char*)LB[cur] + 8192 + bro[i]);
            bl[i] = *reinterpret_cast<const bf16x8*>((const char*)LB[cur] + 16384 + bro[i]);
        }
        #pragma unroll
        for (int mi = 0; mi < 2; ++mi)
            #pragma unroll
            for (int ni = 0; ni < 4; ++ni) {
                f32x4 c = acc[mi][ni];
                c = MFMA16(ah[mi], bh[ni], c);
                c = MFMA16(ah[mi], bl[ni], c);
                acc[mi][ni] = c;
            }
    }

    #pragma unroll
    for (int mi = 0; mi < 2; ++mi) {
        #pragma unroll
        for (int ni = 0; ni < 4; ++ni) {
            int col = bcol + wn * 64 + ni * 16 + l16;
            float bvv = bias[col];
            #pragma unroll
            for (int r = 0; r < 4; ++r) {
                int row = brow + wm * 32 + mi * 16 + quad * 4 + r;
                Cf[(size_t)row * N + col] = acc[mi][ni][r] + bvv;
            }
        }
    }
}

// ---------------------------------------------------------------------------
// V bf16 flat [BH][SEQ][64] -> Vt bf16 [BH][64][SEQ]
// ---------------------------------------------------------------------------
__global__ __launch_bounds__(256) void v_transpose(
    const u16* __restrict__ V, u16* __restrict__ Vt)
{
    __shared__ u16 T[64][72];
    const int bh = blockIdx.y, st = blockIdx.x;
    const u16* src = V + ((size_t)bh * SEQ + (size_t)st * 64) * 64;
    const int t = threadIdx.x;
    #pragma unroll
    for (int i = 0; i < 2; ++i) {
        int c  = t + i * 256;
        int s  = c >> 3;
        int d0 = (c & 7) * 8;
        uint4 v = reinterpret_cast<const uint4*>(src)[c];
        u16 e[8];
        e[0] = (u16)(v.x & 0xffff); e[1] = (u16)(v.x >> 16);
        e[2] = (u16)(v.y & 0xffff); e[3] = (u16)(v.y >> 16);
        e[4] = (u16)(v.z & 0xffff); e[5] = (u16)(v.z >> 16);
        e[6] = (u16)(v.w & 0xffff); e[7] = (u16)(v.w >> 16);
        #pragma unroll
        for (int j = 0; j < 8; ++j) T[d0 + j][s] = e[j];
    }
    __syncthreads();
    const int d = t >> 2, seg = t & 3;
    u16* dst = Vt + (size_t)bh * 64 * SEQ + (size_t)d * SEQ + st * 64 + seg * 16;
    uint4 a = *reinterpret_cast<const uint4*>(&T[d][seg * 16]);
    uint4 b = *reinterpret_cast<const uint4*>(&T[d][seg * 16 + 8]);
    reinterpret_cast<uint4*>(dst)[0] = a;
    reinterpret_cast<uint4*>(dst)[1] = b;
}

// ---------------------------------------------------------------------------
// MFMA flash attention, BARRIER-FREE: K/V fragments loaded direct
// global->VGPR (L1/L2-hot, XCD-local); only Pb (wave-private) in LDS, so the
// kernel has no __syncthreads at all. p = exp2(s) (Q pre-scaled); truncated
// bf16 P; row sums via ones-MFMA on the same P fragments.
// 256 threads, 128-q tile, 32 q-rows/wave; LDS 18 KB; grid 512 (2 blk/CU),
// XCD swizzle bh = id&31.
// ---------------------------------------------------------------------------
__global__ __launch_bounds__(256, 2) void attn_mfma(
    const u16* __restrict__ Qb_g, const u16* __restrict__ Kb_g,
    const u16* __restrict__ Vt_g, u16* __restrict__ Ch_g)
{
    __shared__ u16 Pb[128 * 72];

    const int tid  = threadIdx.x;
    const int wv   = tid >> 6;          // 0..3
    const int lane = tid & 63;
    const int quad = lane >> 4;
    const int l16  = lane & 15;
    const int id   = blockIdx.x;
    const int bh   = id & 31;           // XCD = id%8 = bh%8
    const int qt   = id >> 5;           // 0..15

    const size_t qbase = ((size_t)bh * SEQ + (size_t)qt * 128) * 64;
    const u16* Kt = Kb_g + (size_t)bh * SEQ * 64;
    const u16* Vh = Vt_g + (size_t)bh * 64 * SEQ;

    // ---- Q fragments: direct global -> VGPR (32 q-rows per wave) ----
    bf16x8 qf[2][2];
    #pragma unroll
    for (int sub = 0; sub < 2; ++sub)
        #pragma unroll
        for (int ks = 0; ks < 2; ++ks) {
            size_t o = qbase + (size_t)(wv * 32 + sub * 16 + l16) * 64 + ks * 32 + quad * 8;
            qf[sub][ks] = *reinterpret_cast<const bf16x8*>(Qb_g + o);
        }

    // per-lane fragment offsets
    int kfo[4][2], vfo[4][2];
    #pragma unroll
    for (int t = 0; t < 4; ++t)
        #pragma unroll
        for (int ks = 0; ks < 2; ++ks) {
            kfo[t][ks] = (t * 16 + l16) * 64 + ks * 32 + quad * 8;
            vfo[t][ks] = (t * 16 + l16) * SEQ + ks * 32 + quad * 8;
        }

    bf16x8 onesv;
    #pragma unroll
    for (int i = 0; i < 8; ++i) onesv[i] = (__bf16)1.0f;

    f32x4 oacc[2][4] = {};
    f32x4 lsum[2] = {};

    for (int kt = 0; kt < SEQ / 64; ++kt) {
        const int kofs = kt * 64 * 64;   // K tile byte-row base (in u16 units: 4096)
        const int vofs = kt * 64;        // Vt column base

        // ---- S = Q K^T (K fragments direct from global) ----
        f32x4 sacc[2][4] = {};
        #pragma unroll
        for (int t4 = 0; t4 < 4; ++t4) {
            bf16x8 kh0 = *reinterpret_cast<const bf16x8*>(Kt + kofs + kfo[t4][0]);
            bf16x8 kh1 = *reinterpret_cast<const bf16x8*>(Kt + kofs + kfo[t4][1]);
            #pragma unroll
            for (int sub = 0; sub < 2; ++sub) {
                f32x4 a = sacc[sub][t4];
                a = MFMA16(qf[sub][0], kh0, a);
                a = MFMA16(qf[sub][1], kh1, a);
                sacc[sub][t4] = a;
            }
        }

        // ---- p = exp2(s), truncate to bf16, store to Pb (wave-private) ----
        #pragma unroll
        for (int sub = 0; sub < 2; ++sub) {
            int rowb = wv * 32 + sub * 16 + quad * 4;
            #pragma unroll
            for (int r = 0; r < 4; ++r) {
                u32 u0 = __float_as_uint(__builtin_amdgcn_exp2f(sacc[sub][0][r]));
                u32 u1 = __float_as_uint(__builtin_amdgcn_exp2f(sacc[sub][1][r]));
                u32 u2 = __float_as_uint(__builtin_amdgcn_exp2f(sacc[sub][2][r]));
                u32 u3 = __float_as_uint(__builtin_amdgcn_exp2f(sacc[sub][3][r]));
                int ro = (rowb + r) * 72 + l16;
                Pb[ro +  0] = (u16)(u0 >> 16);
                Pb[ro + 16] = (u16)(u1 >> 16);
                Pb[ro + 32] = (u16)(u2 >> 16);
                Pb[ro + 48] = (u16)(u3 >> 16);
            }
        }

        // ---- O += P @ V ; lsum += P @ 1 (V fragments direct from global) ----
        bf16x8 bv0[4], bv1[4];
        #pragma unroll
        for (int dt = 0; dt < 4; ++dt) {
            bv0[dt] = *reinterpret_cast<const bf16x8*>(Vh + vofs + vfo[dt][0]);
            bv1[dt] = *reinterpret_cast<const bf16x8*>(Vh + vofs + vfo[dt][1]);
        }
        #pragma unroll
        for (int sub = 0; sub < 2; ++sub) {
            bf16x8 ap0 = *reinterpret_cast<const bf16x8*>(
                &Pb[(wv * 32 + sub * 16 + l16) * 72 + 0 + quad * 8]);
            bf16x8 ap1 = *reinterpret_cast<const bf16x8*>(
                &Pb[(wv * 32 + sub * 16 + l16) * 72 + 32 + quad * 8]);
            #pragma unroll
            for (int dt = 0; dt < 4; ++dt) {
                oacc[sub][dt] = MFMA16(ap0, bv0[dt], oacc[sub][dt]);
                oacc[sub][dt] = MFMA16(ap1, bv1[dt], oacc[sub][dt]);
            }
            lsum[sub] = MFMA16(ap0, onesv, lsum[sub]);
            lsum[sub] = MFMA16(ap1, onesv, lsum[sub]);
        }
    }

    // ---- epilogue: normalize by lsum, store ctx bf16 ----
    u16* Oh = Ch_g + qbase;
    #pragma unroll
    for (int sub = 0; sub < 2; ++sub) {
        float inv[4];
        #pragma unroll
        for (int r = 0; r < 4; ++r) inv[r] = 1.0f / lsum[sub][r];
        #pragma unroll
        for (int dt = 0; dt < 4; ++dt)
            #pragma unroll
            for (int r = 0; r < 4; ++r) {
                int row = wv * 32 + sub * 16 + quad * 4 + r;
                Oh[(size_t)row * 64 + dt * 16 + l16] = f2bf(oacc[sub][dt][r] * inv[r]);
            }
    }
}

// ---------------------------------------------------------------------------
extern "C" void kernel_launch(void* const* d_in, const int* in_sizes, int n_in,
                              void* d_out, int out_size, void* d_ws, size_t ws_size,
                              hipStream_t stream)
{
    const float* x  = (const float*)d_in[0];
    const float* Wq = (const float*)d_in[1];
    const float* bq = (const float*)d_in[2];
    const float* Wk = (const float*)d_in[3];
    const float* bk = (const float*)d_in[4];
    const float* Wv = (const float*)d_in[5];
    const float* bv = (const float*)d_in[6];
    const float* Wo = (const float*)d_in[7];
    const float* bo = (const float*)d_in[8];
    float* out = (float*)d_out;

    const int M = BATCH * SEQ;        // 4096
    const int N = D_MODEL;            // 1024
    const size_t NE = (size_t)M * N;  // 4,194,304
    const size_t NW = (size_t)N * N;  // 1,048,576

    u16* w16 = (u16*)d_ws;
    u16* Xh   = w16;
    u16* Qb   = Xh   + NE;
    u16* Kb   = Qb   + NE;
    u16* Vb   = Kb   + NE;
    u16* Vtb  = Vb   + NE;
    u16* Ctxh = Vtb  + NE;
    u16* WTqh = Ctxh + NE;
    u16* WTkh = WTqh + NW;
    u16* WTvh = WTkh + NW;
    u16* WToh = WTvh + NW;
    u16* WTol = WToh + NW;

    // conversions (single launch)
    conv_all<<<dim3(4096 + 1024), dim3(256), 0, stream>>>(
        x, Xh, (int)(NE / 4),
        Wq, Wk, Wv, Wo, WTqh, WTkh, WTvh, WToh, WTol);

    // fused QKV projection (1-term bf16, 512 threads): Q pre-scaled
    gemm_qkv<<<dim3(N / 128, M / 128), dim3(512), 0, stream>>>(
        Xh, WTqh, WTkh, WTvh, bq, bk, bv, Qb, Kb, Vb);

    // transpose V per contiguous reshape slab
    v_transpose<<<dim3(SEQ / 64, BH), dim3(256), 0, stream>>>(Vb, Vtb);

    // attention (barrier-free, direct K/V loads, XCD-swizzled)
    attn_mfma<<<dim3((SEQ / 128) * BH), dim3(256), 0, stream>>>(Qb, Kb, Vtb, Ctxh);

    // output projection (2-term, 512 threads)
    gemm_oproj<<<dim3(N / 128, M / 128), dim3(512), 0, stream>>>(
        Ctxh, WToh, WTol, bo, out);
}